// Round 4
// baseline (168.046 us; speedup 1.0000x reference)
//
#include <hip/hip_runtime.h>

// Problem constants (from reference): B=8, L=2048, H=1024, C=64
#define PB 8
#define PL 2048
#define PH 1024
#define PC 64
#define NROWS (PB * PL)          // 16384

// One wave per feature row. Phase A: dot(feature[row,:], w) via 4x float4
// per lane + full butterfly (__shfl_xor -> every lane holds the dot).
// Phase B: lane k owns span k of this row's batch (C=64 == wave width);
// if l is inside span k, atomically add dot/cnt into out[b*64+k].
// Bias is added exactly once per span, by the row with l == src.
// out must be pre-zeroed (hipMemsetAsync node, dependency-free).
__global__ __launch_bounds__(256) void fused_rowdot_scatter(
    const float* __restrict__ feature,   // [B*L, H]
    const float* __restrict__ w,         // [H]
    const float* __restrict__ bias,      // [1]
    const int2* __restrict__ pos,        // [B*C] (src, end) inclusive
    float* __restrict__ out)             // [B*C], zero-initialized
{
    const int row  = blockIdx.x * 4 + (threadIdx.x >> 6);   // 0..16383
    const int lane = threadIdx.x & 63;
    const int b    = row >> 11;          // row / L
    const int l    = row & (PL - 1);     // row % L

    const float* rp = feature + (size_t)row * PH;

    float acc = 0.0f;
#pragma unroll
    for (int j = 0; j < PH / 256; ++j) {
        const int idx = j * 256 + lane * 4;
        float4 f = *reinterpret_cast<const float4*>(rp + idx);
        float4 g = *reinterpret_cast<const float4*>(w + idx);   // L1-resident
        acc += f.x * g.x + f.y * g.y + f.z * g.z + f.w * g.w;
    }

    // butterfly: all 64 lanes end with the full row dot
#pragma unroll
    for (int m = 1; m < 64; m <<= 1)
        acc += __shfl_xor(acc, m, 64);

    // scatter: lane k <-> span k of batch b
    const int2 se = pos[b * PC + lane];
    if (l >= se.x && l <= se.y) {
        const float cnt = (float)(se.y - se.x + 1);   // src<=end guaranteed
        float v = acc / cnt;
        if (l == se.x) v += bias[0];                   // once per span
        atomicAdd(&out[b * PC + lane], v);
    }
}

extern "C" void kernel_launch(void* const* d_in, const int* in_sizes, int n_in,
                              void* d_out, int out_size, void* d_ws, size_t ws_size,
                              hipStream_t stream) {
    const float* feature = (const float*)d_in[0];   // [B, L, H] fp32
    const float* fc_w    = (const float*)d_in[1];   // [1, H]
    const float* fc_b    = (const float*)d_in[2];   // [1]
    const int2*  pos     = (const int2*)d_in[3];    // [B, C, 2] int32 -> int2
    float*       out     = (float*)d_out;           // [B*C, 1] fp32

    // zero the accumulator output (poisoned to 0xAA by harness)
    hipMemsetAsync(out, 0, PB * PC * sizeof(float), stream);

    // 16384 rows, 1 wave/row, 4 waves/block -> 4096 blocks
    fused_rowdot_scatter<<<NROWS / 4, 256, 0, stream>>>(feature, fc_w, fc_b, pos, out);
}

// Round 5
// 99.712 us; speedup vs baseline: 1.6853x; 1.6853x over previous
//
#include <hip/hip_runtime.h>

// Problem constants (from reference): B=8, L=2048, H=1024, C=64
#define PB 8
#define PL 2048
#define PH 1024
#define PC 64
#define NROWS (PB * PL)          // 16384
#define NSPANS (PB * PC)         // 512

// Kernel 1: s[row] = dot(feature[row,:], w). One wave per row; each lane
// reads 16 floats via 4x float4 (coalesced 1KB/instr per wave), butterfly
// reduce. 16384 waves / 4096 blocks. w (4KB) stays L1-resident.
// Empirically the best config (R1=98.5us); 4-rows-per-wave (R3) and all
// fused variants (R2 grid.sync +190us, R4 atomic scatter +70us) regressed.
__global__ __launch_bounds__(256) void row_dot_kernel(
    const float* __restrict__ feature,   // [B*L, H]
    const float* __restrict__ w,         // [H]
    float* __restrict__ s)               // [B*L]
{
    const int gtid = blockIdx.x * 256 + threadIdx.x;
    const int row  = gtid >> 6;
    const int lane = threadIdx.x & 63;

    const float* rp = feature + (size_t)row * PH;

    float acc = 0.0f;
#pragma unroll
    for (int j = 0; j < PH / 256; ++j) {
        const int idx = j * 256 + lane * 4;
        float4 f = *reinterpret_cast<const float4*>(rp + idx);
        float4 g = *reinterpret_cast<const float4*>(w + idx);
        acc += f.x * g.x + f.y * g.y + f.z * g.z + f.w * g.w;
    }

#pragma unroll
    for (int off = 32; off > 0; off >>= 1)
        acc += __shfl_down(acc, off, 64);

    if (lane == 0) s[row] = acc;
}

// Kernel 2: per (b,c) span, mean of s[b, src..end] + bias. One wave per span.
__global__ __launch_bounds__(256) void span_pool_kernel(
    const float* __restrict__ s,         // [B, L]
    const int* __restrict__ pos,         // [B*C, 2] (src, end) inclusive
    const float* __restrict__ bias,      // [1]
    float* __restrict__ out)             // [B*C]
{
    const int gtid = blockIdx.x * 256 + threadIdx.x;
    const int span = gtid >> 6;          // 0..511
    const int lane = threadIdx.x & 63;

    const int b   = span >> 6;           // span / PC
    const int src = pos[span * 2 + 0];
    const int end = pos[span * 2 + 1];

    const float* sb = s + b * PL;
    float acc = 0.0f;
    for (int l = src + lane; l <= end; l += 64)
        acc += sb[l];

#pragma unroll
    for (int off = 32; off > 0; off >>= 1)
        acc += __shfl_down(acc, off, 64);

    if (lane == 0) {
        const float cnt = (float)(end - src + 1);   // src<=end guaranteed
        out[span] = acc / cnt + bias[0];
    }
}

extern "C" void kernel_launch(void* const* d_in, const int* in_sizes, int n_in,
                              void* d_out, int out_size, void* d_ws, size_t ws_size,
                              hipStream_t stream) {
    const float* feature = (const float*)d_in[0];   // [B, L, H] fp32
    const float* fc_w    = (const float*)d_in[1];   // [1, H]
    const float* fc_b    = (const float*)d_in[2];   // [1]
    const int*   pos     = (const int*)d_in[3];     // [B, C, 2] int32
    float*       out     = (float*)d_out;           // [B*C, 1] fp32
    float*       s       = (float*)d_ws;            // B*L floats = 64 KB scratch

    row_dot_kernel<<<NROWS / 4, 256, 0, stream>>>(feature, fc_w, s);
    span_pool_kernel<<<(NSPANS * 64) / 256, 256, 0, stream>>>(s, pos, fc_b, out);
}